// Round 12
// baseline (245.751 us; speedup 1.0000x reference)
//
#include <hip/hip_runtime.h>

#define B_  4
#define N_  4096
#define C_  256
#define D_  128
#define M_  4095
#define BN_ (B_ * N_)
#define MAXSPLIT 8

typedef _Float16 half_t;
typedef __attribute__((ext_vector_type(8))) _Float16 half8;
typedef __attribute__((ext_vector_type(4))) _Float16 half4;
typedef __attribute__((ext_vector_type(4))) float f32x4;

#define MFMA16x16x32(A, B, C) __builtin_amdgcn_mfma_f32_16x16x32_f16(A, B, C, 0, 0, 0)
#define LOG2E 1.44269504088896f

// ---- prep: weights into B-fragment layouts (runs once, tiny) ----
__global__ __launch_bounds__(256) void prep_kernel(
    const float* __restrict__ Wt, const float* __restrict__ Wp,
    const float* __restrict__ Wg, const float* __restrict__ Wf,
    half_t* __restrict__ WT_hi, half_t* __restrict__ WfT)
{
    const int idx = blockIdx.x * 256 + threadIdx.x;   // 0..32767
    const int wsel = blockIdx.y;
    if (wsel < 3) {
        const float* __restrict__ W = (wsel == 0) ? Wt : (wsel == 1) ? Wp : Wg;
        const int d = idx >> 8, c = idx & 255;
        WT_hi[(size_t)wsel * 32768 + idx] = (half_t)W[(size_t)c * D_ + d];
    } else {
        const int c = idx >> 7, d = idx & 127;
        WfT[idx] = (half_t)Wf[(size_t)d * C_ + c];
    }
}

// ---- proj (single-fp16 MFMA) + FUSED maxpool/transpose (r11, verified) ----
__global__ __launch_bounds__(256) void proj_kernel(
    const float* __restrict__ x, const half_t* __restrict__ WT_hi,
    half_t* __restrict__ theta, half_t* __restrict__ pphi,
    half_t* __restrict__ pgT)
{
    const int tid = threadIdx.x;
    const int lane = tid & 63;
    const int w = tid >> 6;
    const int lm = lane & 15;
    const int lq = lane >> 4;
    const int r0 = blockIdx.x * 64;
    const int which = blockIdx.y;
    const half_t* __restrict__ Wg_ = WT_hi + (size_t)which * 32768;

    __shared__ __align__(16) unsigned char lds_raw[18432];
    half_t (*Xh)[40]  = (half_t (*)[40])(lds_raw);
    half_t (*Whl)[40] = (half_t (*)[40])(lds_raw + 5120);

    f32x4 acc[8];
#pragma unroll
    for (int nb = 0; nb < 8; ++nb)
#pragma unroll
        for (int r = 0; r < 4; ++r) acc[nb][r] = 0.f;

    const int xr = tid >> 2, xc = (tid & 3) * 8;
    const int wr = tid >> 1, wc = (tid & 1) * 16;

    for (int kc = 0; kc < 8; ++kc) {
        __syncthreads();
        {
            const float* xs = x + (size_t)(r0 + xr) * C_ + kc * 32 + xc;
            float4 v0 = *(const float4*)&xs[0], v1 = *(const float4*)&xs[4];
            half8 hi;
            hi[0] = (half_t)v0.x; hi[1] = (half_t)v0.y;
            hi[2] = (half_t)v0.z; hi[3] = (half_t)v0.w;
            hi[4] = (half_t)v1.x; hi[5] = (half_t)v1.y;
            hi[6] = (half_t)v1.z; hi[7] = (half_t)v1.w;
            *(half8*)&Xh[xr][xc] = hi;
            const half_t* wsrc = Wg_ + (size_t)wr * 256 + kc * 32 + wc;
            *(half8*)&Whl[wr][wc]     = *(const half8*)&wsrc[0];
            *(half8*)&Whl[wr][wc + 8] = *(const half8*)&wsrc[8];
        }
        __syncthreads();

        half8 ah = *(const half8*)&Xh[w * 16 + lm][lq * 8];
#pragma unroll
        for (int nb = 0; nb < 8; ++nb) {
            half8 bh = *(const half8*)&Whl[nb * 16 + lm][lq * 8];
            acc[nb] = MFMA16x16x32(ah, bh, acc[nb]);
        }
    }

    if (which == 0) {
#pragma unroll
        for (int nb = 0; nb < 8; ++nb)
#pragma unroll
            for (int r = 0; r < 4; ++r)
                theta[(size_t)(r0 + w * 16 + lq * 4 + r) * D_ + nb * 16 + lm] =
                    (half_t)(acc[nb][r] * LOG2E);
        return;
    }

    __syncthreads();
    half_t (*LsT)[72] = (half_t (*)[72])(lds_raw);
#pragma unroll
    for (int nb = 0; nb < 8; ++nb) {
        const int d = nb * 16 + lm;
        const int m = w * 16 + lq * 4;
        half4 pk;
#pragma unroll
        for (int r = 0; r < 4; ++r) pk[r] = (half_t)acc[nb][r];
        *(half4*)&LsT[d][m] = pk;
    }
    if (tid < 128) {
        int rh = r0 + 64;
        if ((rh & (N_ - 1)) == 0) rh = r0 + 63;
        const float* xrow = x + (size_t)rh * C_;
        const half_t* wrow = Wg_ + (size_t)tid * 256;
        float s = 0.f;
#pragma unroll
        for (int c8 = 0; c8 < 32; ++c8) {
            half8 h = *(const half8*)&wrow[c8 * 8];
            float4 xa = *(const float4*)&xrow[c8 * 8];
            float4 xb = *(const float4*)&xrow[c8 * 8 + 4];
            s += xa.x * (float)h[0] + xa.y * (float)h[1]
               + xa.z * (float)h[2] + xa.w * (float)h[3]
               + xb.x * (float)h[4] + xb.y * (float)h[5]
               + xb.z * (float)h[6] + xb.w * (float)h[7];
        }
        LsT[tid][64] = (half_t)s;
    }
    __syncthreads();

    if (which == 1) {
        const int m = tid >> 2, dh = (tid & 3) * 32;
        half8 o[4];
#pragma unroll
        for (int j = 0; j < 32; ++j) {
            float v0 = (float)LsT[dh + j][m];
            float v1 = (float)LsT[dh + j][m + 1];
            o[j >> 3][j & 7] = (half_t)fmaxf(v0, v1);
        }
        half8* dst = (half8*)&pphi[(size_t)(r0 + m) * D_ + dh];
#pragma unroll
        for (int j = 0; j < 4; ++j) dst[j] = o[j];
    } else {
        const int d = tid >> 1, mh = (tid & 1) * 32;
        const int b = r0 / N_, m0 = r0 & (N_ - 1);
        half8 in[4];
#pragma unroll
        for (int j = 0; j < 4; ++j) in[j] = *(const half8*)&LsT[d][mh + j * 8];
        const half_t ext = LsT[d][mh + 32];
        half8 o[4];
#pragma unroll
        for (int j = 0; j < 32; ++j) {
            float v0 = (float)in[j >> 3][j & 7];
            float v1 = (j == 31) ? (float)ext : (float)in[(j + 1) >> 3][(j + 1) & 7];
            o[j >> 3][j & 7] = (half_t)fmaxf(v0, v1);
        }
        half8* dst = (half8*)&pgT[((size_t)b * D_ + d) * N_ + m0 + mh];
#pragma unroll
        for (int j = 0; j < 4; ++j) dst[j] = o[j];
    }
}

// ---------------- MFMA flash attention: Ps-over-Ks overlay ----------------
// LDS = 36,864 B -> 4 blocks/CU (16 waves). grid (32, nsplit, 4); nsplit is
// runtime (8 if ws fits, else 4). 3 barriers/ktile (extra one lets P-stores
// safely clobber the Ks region after all waves finish QK reads).
__global__ __launch_bounds__(256, 4) void attn_kernel(
    const half_t* __restrict__ theta, const half_t* __restrict__ pphi,
    const half_t* __restrict__ pgT, half_t* __restrict__ ypart,
    float* __restrict__ mstat, float* __restrict__ lstat, int nsplit)
{
    const int tid = threadIdx.x;
    const int lane = tid & 63;
    const int w = tid >> 6;
    const int lm = lane & 15;
    const int lq = lane >> 4;      // 0..3
    const int qt = blockIdx.x, ksb = blockIdx.y, b = blockIdx.z;
    const int q0 = qt * 128;
    const int kt0 = (64 * ksb) / nsplit;
    const int kt1 = (64 * (ksb + 1)) / nsplit;

    __shared__ __align__(16) unsigned char lds_raw[36864];
    half_t (*Ks)[136] = (half_t (*)[136])(lds_raw);          // 17,408 (QK phase)
    half_t (*Ps)[72]  = (half_t (*)[72])(lds_raw);           // 18,432 (PV phase)
    half_t (*Gts)[72] = (half_t (*)[72])(lds_raw + 18432);   // 18,432

    // Q B-frags (B[k=d][n=q]): direct fp16 loads (theta already *log2e)
    half8 qh[2][4];
#pragma unroll
    for (int nb = 0; nb < 2; ++nb) {
        const half_t* tr_ = theta + ((size_t)b * N_ + q0 + w * 32 + nb * 16 + lm) * D_;
#pragma unroll
        for (int k4 = 0; k4 < 4; ++k4)
            qh[nb][k4] = *(const half8*)(tr_ + k4 * 32 + lq * 8);
    }

    float m_i[2] = {-1e30f, -1e30f};
    float l_i[2] = {0.f, 0.f};      // per-quad partial; cross-quad sum deferred
    f32x4 yacc[2][8];
#pragma unroll
    for (int mb = 0; mb < 2; ++mb)
#pragma unroll
        for (int dn = 0; dn < 8; ++dn)
#pragma unroll
            for (int r = 0; r < 4; ++r) yacc[mb][dn][r] = 0.f;

    for (int kt = kt0; kt < kt1; ++kt) {
        const int k0 = kt * 64;
        __syncthreads();   // (A) prev PV done reading Ps(overlay) + Gts
        {   // stage K [key][d] and G^T [d][key] cooperatively (coalesced)
            const int key = tid >> 2, ch = (tid & 3);
            const float4* src = (const float4*)(pphi +
                ((size_t)b * N_ + k0 + key) * D_ + ch * 32);
            float4 a0 = src[0], a1 = src[1], a2 = src[2], a3 = src[3];
            float4* dst = (float4*)&Ks[key][ch * 32];
            dst[0] = a0; dst[1] = a1; dst[2] = a2; dst[3] = a3;
            const int d = tid >> 1, kh = (tid & 1);
            const float4* gs = (const float4*)(pgT +
                ((size_t)b * D_ + d) * N_ + k0 + kh * 32);
            float4 g0 = gs[0], g1 = gs[1], g2 = gs[2], g3 = gs[3];
            float4* gd = (float4*)&Gts[d][kh * 32];
            gd[0] = g0; gd[1] = g1; gd[2] = g2; gd[3] = g3;
        }
        __syncthreads();   // (B) staging visible

        // QK^T transposed: S^T[key][q]; A = K (LDS), B = Q (regs)
        f32x4 sc[4][2];
#pragma unroll
        for (int kb = 0; kb < 4; ++kb)
#pragma unroll
            for (int nb = 0; nb < 2; ++nb)
#pragma unroll
                for (int r = 0; r < 4; ++r) sc[kb][nb][r] = 0.f;
#pragma unroll
        for (int kb = 0; kb < 4; ++kb) {
#pragma unroll
            for (int k4 = 0; k4 < 4; ++k4) {
                half8 kf = *(const half8*)&Ks[kb * 16 + lm][k4 * 32 + lq * 8];
#pragma unroll
                for (int nb = 0; nb < 2; ++nb)
                    sc[kb][nb] = MFMA16x16x32(kf, qh[nb][k4], sc[kb][nb]);
            }
        }
        // mask padded key 4095 (only last tile of last split)
        if (k0 + 64 > M_) {
#pragma unroll
            for (int kb = 0; kb < 4; ++kb)
#pragma unroll
                for (int r = 0; r < 4; ++r)
                    if (k0 + kb * 16 + lq * 4 + r >= M_) {
                        sc[kb][0][r] = -1e30f; sc[kb][1][r] = -1e30f;
                    }
        }
        // online softmax (base-2): in-lane over 16 keys + 2 cross-quad max
        // shuffles; l stays per-quad partial. All in registers (pre-barrier).
        float alpha[2];
#pragma unroll
        for (int nb = 0; nb < 2; ++nb) {
            float mt = -1e30f;
#pragma unroll
            for (int kb = 0; kb < 4; ++kb)
#pragma unroll
                for (int r = 0; r < 4; ++r) mt = fmaxf(mt, sc[kb][nb][r]);
            mt = fmaxf(mt, __shfl_xor(mt, 16, 64));
            mt = fmaxf(mt, __shfl_xor(mt, 32, 64));
            const float mnew = fmaxf(m_i[nb], mt);
            alpha[nb] = exp2f(m_i[nb] - mnew);
            m_i[nb] = mnew;
            float rs = 0.f;
#pragma unroll
            for (int kb = 0; kb < 4; ++kb)
#pragma unroll
                for (int r = 0; r < 4; ++r) {
                    float p = exp2f(sc[kb][nb][r] - mnew);
                    sc[kb][nb][r] = p;
                    rs += p;
                }
            l_i[nb] = l_i[nb] * alpha[nb] + rs;
        }
        // transpose alpha from (q=lm) lane layout to accumulator's (q=lq*4+r)
        float alpha_t[2][4];
#pragma unroll
        for (int mb = 0; mb < 2; ++mb)
#pragma unroll
            for (int r = 0; r < 4; ++r)
                alpha_t[mb][r] = __shfl(alpha[mb], lq * 4 + r, 16);
        // rescale accumulator
#pragma unroll
        for (int mb = 0; mb < 2; ++mb)
#pragma unroll
            for (int dn = 0; dn < 8; ++dn)
#pragma unroll
                for (int r = 0; r < 4; ++r) yacc[mb][dn][r] *= alpha_t[mb][r];

        __syncthreads();   // (C) all waves done reading Ks -> Ps may clobber
        // P store: 4 consecutive keys at fixed q -> one b64 per (nb,kb)
#pragma unroll
        for (int nb = 0; nb < 2; ++nb)
#pragma unroll
            for (int kb = 0; kb < 4; ++kb) {
                half4 pk;
#pragma unroll
                for (int r = 0; r < 4; ++r) pk[r] = (half_t)sc[kb][nb][r];
                *(half4*)&Ps[w * 32 + nb * 16 + lm][kb * 16 + lq * 4] = pk;
            }
        // PV: A = P (LDS, wave-private rows -> program order suffices), B = G^T
        half8 pf[2][2];
#pragma unroll
        for (int mb = 0; mb < 2; ++mb)
#pragma unroll
            for (int k2 = 0; k2 < 2; ++k2)
                pf[mb][k2] = *(const half8*)&Ps[w * 32 + mb * 16 + lm][k2 * 32 + lq * 8];
#pragma unroll
        for (int dn = 0; dn < 8; ++dn) {
#pragma unroll
            for (int k2 = 0; k2 < 2; ++k2) {
                half8 gf = *(const half8*)&Gts[dn * 16 + lm][k2 * 32 + lq * 8];
                yacc[0][dn] = MFMA16x16x32(pf[0][k2], gf, yacc[0][dn]);
                yacc[1][dn] = MFMA16x16x32(pf[1][k2], gf, yacc[1][dn]);
            }
        }
    }

    // epilogue: finish l (cross-quad sum, deferred from the k-loop)
#pragma unroll
    for (int nb = 0; nb < 2; ++nb) {
        l_i[nb] += __shfl_xor(l_i[nb], 16, 64);
        l_i[nb] += __shfl_xor(l_i[nb], 32, 64);
    }
    // unnormalized y partial (fp16) + (m,l) stats (m in base-2)
    half_t* yp = ypart + ((size_t)ksb * BN_ + (size_t)b * N_) * D_;
#pragma unroll
    for (int mb = 0; mb < 2; ++mb)
#pragma unroll
        for (int dn = 0; dn < 8; ++dn)
#pragma unroll
            for (int r = 0; r < 4; ++r)
                yp[(size_t)(q0 + w * 32 + mb * 16 + lq * 4 + r) * D_ + dn * 16 + lm] =
                    (half_t)yacc[mb][dn][r];
    if (lq == 0) {
#pragma unroll
        for (int nb = 0; nb < 2; ++nb) {
            const int row = q0 + w * 32 + nb * 16 + lm;
            mstat[(size_t)ksb * BN_ + (size_t)b * N_ + row] = m_i[nb];
            lstat[(size_t)ksb * BN_ + (size_t)b * N_ + row] = l_i[nb];
        }
    }
}

// ---- final (MFMA): merge nsplit partials (base-2 stats), z = x + y @ Wf ----
// grid (BN_/128, 2), block 256. LDS = 40,960 B.
__global__ __launch_bounds__(256) void final_kernel(
    const half_t* __restrict__ ypart, const float* __restrict__ mstat,
    const float* __restrict__ lstat, const float* __restrict__ x,
    const half_t* __restrict__ WfT, float* __restrict__ out, int nsplit)
{
    const int tid = threadIdx.x;
    const int lane = tid & 63;
    const int w = tid >> 6;
    const int lm = lane & 15;
    const int lq = lane >> 4;
    const int r0 = blockIdx.x * 128;
    const int c0 = blockIdx.y * 128;

    __shared__ half_t Ys[128][72];
    __shared__ half_t Wfs[128][72];
    __shared__ float scl[MAXSPLIT][128];

    if (tid < 128) {
        const int row = r0 + tid;
        float mv[MAXSPLIT], lv[MAXSPLIT];
        float Mx = -1e30f;
        for (int s = 0; s < nsplit; ++s) {
            mv[s] = mstat[(size_t)s * BN_ + row];
            lv[s] = lstat[(size_t)s * BN_ + row];
            Mx = fmaxf(Mx, mv[s]);
        }
        float lsum = 0.f;
        float wv[MAXSPLIT];
        for (int s = 0; s < nsplit; ++s) { wv[s] = exp2f(mv[s] - Mx); lsum += wv[s] * lv[s]; }
        const float inv = 1.f / lsum;
        for (int s = 0; s < nsplit; ++s) scl[s][tid] = wv[s] * inv;
    }
    __syncthreads();

    f32x4 acc[2][8];
#pragma unroll
    for (int rb = 0; rb < 2; ++rb)
#pragma unroll
        for (int nb = 0; nb < 8; ++nb)
#pragma unroll
            for (int r = 0; r < 4; ++r) acc[rb][nb][r] = 0.f;

    const int sr = tid >> 1;
    const int dd = (tid & 1) * 32;

    for (int kc = 0; kc < 2; ++kc) {
        {
            const size_t yb = (size_t)(r0 + sr) * D_ + kc * 64 + dd;
            half8 o[4];
#pragma unroll
            for (int q = 0; q < 4; ++q) {
                float m[8];
#pragma unroll
                for (int j = 0; j < 8; ++j) m[j] = 0.f;
                for (int s = 0; s < nsplit; ++s) {
                    const float ss = scl[s][sr];
                    half8 yv = *(const half8*)&ypart[(size_t)s * BN_ * D_ + yb + q * 8];
#pragma unroll
                    for (int j = 0; j < 8; ++j) m[j] += ss * (float)yv[j];
                }
#pragma unroll
                for (int j = 0; j < 8; ++j) o[q][j] = (half_t)m[j];
            }
#pragma unroll
            for (int q = 0; q < 4; ++q) *(half8*)&Ys[sr][dd + q * 8] = o[q];
            const half_t* wf = WfT + (size_t)(c0 + sr) * D_ + kc * 64 + dd;
#pragma unroll
            for (int q = 0; q < 4; ++q)
                *(half8*)&Wfs[sr][dd + q * 8] = *(const half8*)&wf[q * 8];
        }
        __syncthreads();

        half8 af[2][2];
#pragma unroll
        for (int rb = 0; rb < 2; ++rb)
#pragma unroll
            for (int k2 = 0; k2 < 2; ++k2)
                af[rb][k2] = *(const half8*)&Ys[w * 32 + rb * 16 + lm][k2 * 32 + lq * 8];
#pragma unroll
        for (int nb = 0; nb < 8; ++nb) {
#pragma unroll
            for (int k2 = 0; k2 < 2; ++k2) {
                half8 bf = *(const half8*)&Wfs[nb * 16 + lm][k2 * 32 + lq * 8];
                acc[0][nb] = MFMA16x16x32(af[0][k2], bf, acc[0][nb]);
                acc[1][nb] = MFMA16x16x32(af[1][k2], bf, acc[1][nb]);
            }
        }
        __syncthreads();
    }
#pragma unroll
    for (int rb = 0; rb < 2; ++rb)
#pragma unroll
        for (int nb = 0; nb < 8; ++nb)
#pragma unroll
            for (int r = 0; r < 4; ++r) {
                const int row = r0 + w * 32 + rb * 16 + lq * 4 + r;
                const int col = c0 + nb * 16 + lm;
                out[(size_t)row * C_ + col] =
                    acc[rb][nb][r] + x[(size_t)row * C_ + col];
            }
}

extern "C" void kernel_launch(void* const* d_in, const int* in_sizes, int n_in,
                              void* d_out, int out_size, void* d_ws, size_t ws_size,
                              hipStream_t stream)
{
    const float* x  = (const float*)d_in[0];
    const float* Wt = (const float*)d_in[1];
    const float* Wp = (const float*)d_in[2];
    const float* Wg = (const float*)d_in[3];
    const float* Wf = (const float*)d_in[4];
    float* out = (float*)d_out;

    const size_t SEG = (size_t)BN_ * D_;   // 2,097,152 fp32 words
    // words(k) = theta+pphi+pgT (1.5 SEG) + ypart (k*SEG/2) + stats (2k*BN_)
    //            + WT_hi (49152) + WfT (16384)
    const size_t words8 = 3 * SEG / 2 + 8 * SEG / 2 + (size_t)2 * 8 * BN_ + 65536;
    const int nsplit = (ws_size >= words8 * sizeof(float)) ? 8 : 4;

    float* ws     = (float*)d_ws;
    half_t* theta = (half_t*)ws;
    half_t* pphi  = (half_t*)(ws + SEG / 2);
    half_t* pgT   = (half_t*)(ws + SEG);
    half_t* ypart = (half_t*)(ws + 3 * SEG / 2);
    float* mstat  = ws + 3 * SEG / 2 + (size_t)nsplit * SEG / 2;
    float* lstat  = mstat + (size_t)nsplit * BN_;
    half_t* WT_hi = (half_t*)(lstat + (size_t)nsplit * BN_);
    half_t* WfT   = WT_hi + 3 * 32768;

    prep_kernel<<<dim3(128, 4), 256, 0, stream>>>(Wt, Wp, Wg, Wf, WT_hi, WfT);
    proj_kernel<<<dim3(BN_ / 64, 3), 256, 0, stream>>>(x, WT_hi, theta, pphi, pgT);
    attn_kernel<<<dim3(N_ / 128, nsplit, B_), 256, 0, stream>>>(
        theta, pphi, pgT, ypart, mstat, lstat, nsplit);
    final_kernel<<<dim3(BN_ / 128, 2), 256, 0, stream>>>(
        ypart, mstat, lstat, x, WfT, out, nsplit);
}

// Round 13
// 185.946 us; speedup vs baseline: 1.3216x; 1.3216x over previous
//
#include <hip/hip_runtime.h>

#define B_  4
#define N_  4096
#define C_  256
#define D_  128
#define M_  4095
#define BN_ (B_ * N_)
#define MAXSPLIT 8

typedef _Float16 half_t;
typedef __attribute__((ext_vector_type(8))) _Float16 half8;
typedef __attribute__((ext_vector_type(4))) _Float16 half4;
typedef __attribute__((ext_vector_type(4))) float f32x4;

#define MFMA16x16x32(A, B, C) __builtin_amdgcn_mfma_f32_16x16x32_f16(A, B, C, 0, 0, 0)
#define LOG2E 1.44269504088896f

// ---- prep: weights into B-fragment layouts (runs once, tiny) ----
__global__ __launch_bounds__(256) void prep_kernel(
    const float* __restrict__ Wt, const float* __restrict__ Wp,
    const float* __restrict__ Wg, const float* __restrict__ Wf,
    half_t* __restrict__ WT_hi, half_t* __restrict__ WfT)
{
    const int idx = blockIdx.x * 256 + threadIdx.x;   // 0..32767
    const int wsel = blockIdx.y;
    if (wsel < 3) {
        const float* __restrict__ W = (wsel == 0) ? Wt : (wsel == 1) ? Wp : Wg;
        const int d = idx >> 8, c = idx & 255;
        WT_hi[(size_t)wsel * 32768 + idx] = (half_t)W[(size_t)c * D_ + d];
    } else {
        const int c = idx >> 7, d = idx & 127;
        WfT[idx] = (half_t)Wf[(size_t)d * C_ + c];
    }
}

// ---- proj (single-fp16 MFMA) + FUSED maxpool/transpose (r11, verified) ----
__global__ __launch_bounds__(256) void proj_kernel(
    const float* __restrict__ x, const half_t* __restrict__ WT_hi,
    half_t* __restrict__ theta, half_t* __restrict__ pphi,
    half_t* __restrict__ pgT)
{
    const int tid = threadIdx.x;
    const int lane = tid & 63;
    const int w = tid >> 6;
    const int lm = lane & 15;
    const int lq = lane >> 4;
    const int r0 = blockIdx.x * 64;
    const int which = blockIdx.y;
    const half_t* __restrict__ Wg_ = WT_hi + (size_t)which * 32768;

    __shared__ __align__(16) unsigned char lds_raw[18432];
    half_t (*Xh)[40]  = (half_t (*)[40])(lds_raw);
    half_t (*Whl)[40] = (half_t (*)[40])(lds_raw + 5120);

    f32x4 acc[8];
#pragma unroll
    for (int nb = 0; nb < 8; ++nb)
#pragma unroll
        for (int r = 0; r < 4; ++r) acc[nb][r] = 0.f;

    const int xr = tid >> 2, xc = (tid & 3) * 8;
    const int wr = tid >> 1, wc = (tid & 1) * 16;

    for (int kc = 0; kc < 8; ++kc) {
        __syncthreads();
        {
            const float* xs = x + (size_t)(r0 + xr) * C_ + kc * 32 + xc;
            float4 v0 = *(const float4*)&xs[0], v1 = *(const float4*)&xs[4];
            half8 hi;
            hi[0] = (half_t)v0.x; hi[1] = (half_t)v0.y;
            hi[2] = (half_t)v0.z; hi[3] = (half_t)v0.w;
            hi[4] = (half_t)v1.x; hi[5] = (half_t)v1.y;
            hi[6] = (half_t)v1.z; hi[7] = (half_t)v1.w;
            *(half8*)&Xh[xr][xc] = hi;
            const half_t* wsrc = Wg_ + (size_t)wr * 256 + kc * 32 + wc;
            *(half8*)&Whl[wr][wc]     = *(const half8*)&wsrc[0];
            *(half8*)&Whl[wr][wc + 8] = *(const half8*)&wsrc[8];
        }
        __syncthreads();

        half8 ah = *(const half8*)&Xh[w * 16 + lm][lq * 8];
#pragma unroll
        for (int nb = 0; nb < 8; ++nb) {
            half8 bh = *(const half8*)&Whl[nb * 16 + lm][lq * 8];
            acc[nb] = MFMA16x16x32(ah, bh, acc[nb]);
        }
    }

    if (which == 0) {
#pragma unroll
        for (int nb = 0; nb < 8; ++nb)
#pragma unroll
            for (int r = 0; r < 4; ++r)
                theta[(size_t)(r0 + w * 16 + lq * 4 + r) * D_ + nb * 16 + lm] =
                    (half_t)(acc[nb][r] * LOG2E);
        return;
    }

    __syncthreads();
    half_t (*LsT)[72] = (half_t (*)[72])(lds_raw);
#pragma unroll
    for (int nb = 0; nb < 8; ++nb) {
        const int d = nb * 16 + lm;
        const int m = w * 16 + lq * 4;
        half4 pk;
#pragma unroll
        for (int r = 0; r < 4; ++r) pk[r] = (half_t)acc[nb][r];
        *(half4*)&LsT[d][m] = pk;
    }
    if (tid < 128) {
        int rh = r0 + 64;
        if ((rh & (N_ - 1)) == 0) rh = r0 + 63;
        const float* xrow = x + (size_t)rh * C_;
        const half_t* wrow = Wg_ + (size_t)tid * 256;
        float s = 0.f;
#pragma unroll
        for (int c8 = 0; c8 < 32; ++c8) {
            half8 h = *(const half8*)&wrow[c8 * 8];
            float4 xa = *(const float4*)&xrow[c8 * 8];
            float4 xb = *(const float4*)&xrow[c8 * 8 + 4];
            s += xa.x * (float)h[0] + xa.y * (float)h[1]
               + xa.z * (float)h[2] + xa.w * (float)h[3]
               + xb.x * (float)h[4] + xb.y * (float)h[5]
               + xb.z * (float)h[6] + xb.w * (float)h[7];
        }
        LsT[tid][64] = (half_t)s;
    }
    __syncthreads();

    if (which == 1) {
        const int m = tid >> 2, dh = (tid & 3) * 32;
        half8 o[4];
#pragma unroll
        for (int j = 0; j < 32; ++j) {
            float v0 = (float)LsT[dh + j][m];
            float v1 = (float)LsT[dh + j][m + 1];
            o[j >> 3][j & 7] = (half_t)fmaxf(v0, v1);
        }
        half8* dst = (half8*)&pphi[(size_t)(r0 + m) * D_ + dh];
#pragma unroll
        for (int j = 0; j < 4; ++j) dst[j] = o[j];
    } else {
        const int d = tid >> 1, mh = (tid & 1) * 32;
        const int b = r0 / N_, m0 = r0 & (N_ - 1);
        half8 in[4];
#pragma unroll
        for (int j = 0; j < 4; ++j) in[j] = *(const half8*)&LsT[d][mh + j * 8];
        const half_t ext = LsT[d][mh + 32];
        half8 o[4];
#pragma unroll
        for (int j = 0; j < 32; ++j) {
            float v0 = (float)in[j >> 3][j & 7];
            float v1 = (j == 31) ? (float)ext : (float)in[(j + 1) >> 3][(j + 1) & 7];
            o[j >> 3][j & 7] = (half_t)fmaxf(v0, v1);
        }
        half8* dst = (half8*)&pgT[((size_t)b * D_ + d) * N_ + m0 + mh];
#pragma unroll
        for (int j = 0; j < 4; ++j) dst[j] = o[j];
    }
}

// ---------------- MFMA flash attention: Ps-over-Ks overlay ----------------
// LDS = 36,864 B -> HW fits 4 blocks/CU by LDS; launch_bounds kept at the
// PROVEN (256,2) so the register allocator stays at ~92 VGPR (r12's (256,4)
// crushed it to 64 and spilled ~500 MB to scratch). grid (32, nsplit, 4).
__global__ __launch_bounds__(256, 2) void attn_kernel(
    const half_t* __restrict__ theta, const half_t* __restrict__ pphi,
    const half_t* __restrict__ pgT, half_t* __restrict__ ypart,
    float* __restrict__ mstat, float* __restrict__ lstat, int nsplit)
{
    const int tid = threadIdx.x;
    const int lane = tid & 63;
    const int w = tid >> 6;
    const int lm = lane & 15;
    const int lq = lane >> 4;      // 0..3
    const int qt = blockIdx.x, ksb = blockIdx.y, b = blockIdx.z;
    const int q0 = qt * 128;
    const int kt0 = (64 * ksb) / nsplit;
    const int kt1 = (64 * (ksb + 1)) / nsplit;

    __shared__ __align__(16) unsigned char lds_raw[36864];
    half_t (*Ks)[136] = (half_t (*)[136])(lds_raw);          // 17,408 (QK phase)
    half_t (*Ps)[72]  = (half_t (*)[72])(lds_raw);           // 18,432 (PV phase)
    half_t (*Gts)[72] = (half_t (*)[72])(lds_raw + 18432);   // 18,432

    // Q B-frags (B[k=d][n=q]): direct fp16 loads (theta already *log2e)
    half8 qh[2][4];
#pragma unroll
    for (int nb = 0; nb < 2; ++nb) {
        const half_t* tr_ = theta + ((size_t)b * N_ + q0 + w * 32 + nb * 16 + lm) * D_;
#pragma unroll
        for (int k4 = 0; k4 < 4; ++k4)
            qh[nb][k4] = *(const half8*)(tr_ + k4 * 32 + lq * 8);
    }

    float m_i[2] = {-1e30f, -1e30f};
    float l_i[2] = {0.f, 0.f};      // per-quad partial; cross-quad sum deferred
    f32x4 yacc[2][8];
#pragma unroll
    for (int mb = 0; mb < 2; ++mb)
#pragma unroll
        for (int dn = 0; dn < 8; ++dn)
#pragma unroll
            for (int r = 0; r < 4; ++r) yacc[mb][dn][r] = 0.f;

    for (int kt = kt0; kt < kt1; ++kt) {
        const int k0 = kt * 64;
        __syncthreads();   // (A) prev PV done reading Ps(overlay) + Gts
        {   // stage K [key][d] and G^T [d][key] cooperatively (coalesced)
            const int key = tid >> 2, ch = (tid & 3);
            const float4* src = (const float4*)(pphi +
                ((size_t)b * N_ + k0 + key) * D_ + ch * 32);
            float4 a0 = src[0], a1 = src[1], a2 = src[2], a3 = src[3];
            float4* dst = (float4*)&Ks[key][ch * 32];
            dst[0] = a0; dst[1] = a1; dst[2] = a2; dst[3] = a3;
            const int d = tid >> 1, kh = (tid & 1);
            const float4* gs = (const float4*)(pgT +
                ((size_t)b * D_ + d) * N_ + k0 + kh * 32);
            float4 g0 = gs[0], g1 = gs[1], g2 = gs[2], g3 = gs[3];
            float4* gd = (float4*)&Gts[d][kh * 32];
            gd[0] = g0; gd[1] = g1; gd[2] = g2; gd[3] = g3;
        }
        __syncthreads();   // (B) staging visible

        // QK^T transposed: S^T[key][q]; A = K (LDS), B = Q (regs)
        f32x4 sc[4][2];
#pragma unroll
        for (int kb = 0; kb < 4; ++kb)
#pragma unroll
            for (int nb = 0; nb < 2; ++nb)
#pragma unroll
                for (int r = 0; r < 4; ++r) sc[kb][nb][r] = 0.f;
#pragma unroll
        for (int kb = 0; kb < 4; ++kb) {
#pragma unroll
            for (int k4 = 0; k4 < 4; ++k4) {
                half8 kf = *(const half8*)&Ks[kb * 16 + lm][k4 * 32 + lq * 8];
#pragma unroll
                for (int nb = 0; nb < 2; ++nb)
                    sc[kb][nb] = MFMA16x16x32(kf, qh[nb][k4], sc[kb][nb]);
            }
        }
        // mask padded key 4095 (only last tile of last split)
        if (k0 + 64 > M_) {
#pragma unroll
            for (int kb = 0; kb < 4; ++kb)
#pragma unroll
                for (int r = 0; r < 4; ++r)
                    if (k0 + kb * 16 + lq * 4 + r >= M_) {
                        sc[kb][0][r] = -1e30f; sc[kb][1][r] = -1e30f;
                    }
        }
        // online softmax (base-2): in-lane over 16 keys + 2 cross-quad max
        // shuffles; l stays per-quad partial. All in registers (pre-barrier).
        float alpha[2];
#pragma unroll
        for (int nb = 0; nb < 2; ++nb) {
            float mt = -1e30f;
#pragma unroll
            for (int kb = 0; kb < 4; ++kb)
#pragma unroll
                for (int r = 0; r < 4; ++r) mt = fmaxf(mt, sc[kb][nb][r]);
            mt = fmaxf(mt, __shfl_xor(mt, 16, 64));
            mt = fmaxf(mt, __shfl_xor(mt, 32, 64));
            const float mnew = fmaxf(m_i[nb], mt);
            alpha[nb] = exp2f(m_i[nb] - mnew);
            m_i[nb] = mnew;
            float rs = 0.f;
#pragma unroll
            for (int kb = 0; kb < 4; ++kb)
#pragma unroll
                for (int r = 0; r < 4; ++r) {
                    float p = exp2f(sc[kb][nb][r] - mnew);
                    sc[kb][nb][r] = p;
                    rs += p;
                }
            l_i[nb] = l_i[nb] * alpha[nb] + rs;
        }
        // transpose alpha from (q=lm) lane layout to accumulator's (q=lq*4+r)
        float alpha_t[2][4];
#pragma unroll
        for (int mb = 0; mb < 2; ++mb)
#pragma unroll
            for (int r = 0; r < 4; ++r)
                alpha_t[mb][r] = __shfl(alpha[mb], lq * 4 + r, 16);
        // rescale accumulator
#pragma unroll
        for (int mb = 0; mb < 2; ++mb)
#pragma unroll
            for (int dn = 0; dn < 8; ++dn)
#pragma unroll
                for (int r = 0; r < 4; ++r) yacc[mb][dn][r] *= alpha_t[mb][r];

        __syncthreads();   // (C) all waves done reading Ks -> Ps may clobber
        // P store: 4 consecutive keys at fixed q -> one b64 per (nb,kb)
#pragma unroll
        for (int nb = 0; nb < 2; ++nb)
#pragma unroll
            for (int kb = 0; kb < 4; ++kb) {
                half4 pk;
#pragma unroll
                for (int r = 0; r < 4; ++r) pk[r] = (half_t)sc[kb][nb][r];
                *(half4*)&Ps[w * 32 + nb * 16 + lm][kb * 16 + lq * 4] = pk;
            }
        // PV: A = P (LDS, wave-private rows -> program order suffices), B = G^T
        half8 pf[2][2];
#pragma unroll
        for (int mb = 0; mb < 2; ++mb)
#pragma unroll
            for (int k2 = 0; k2 < 2; ++k2)
                pf[mb][k2] = *(const half8*)&Ps[w * 32 + mb * 16 + lm][k2 * 32 + lq * 8];
#pragma unroll
        for (int dn = 0; dn < 8; ++dn) {
#pragma unroll
            for (int k2 = 0; k2 < 2; ++k2) {
                half8 gf = *(const half8*)&Gts[dn * 16 + lm][k2 * 32 + lq * 8];
                yacc[0][dn] = MFMA16x16x32(pf[0][k2], gf, yacc[0][dn]);
                yacc[1][dn] = MFMA16x16x32(pf[1][k2], gf, yacc[1][dn]);
            }
        }
    }

    // epilogue: finish l (cross-quad sum, deferred from the k-loop)
#pragma unroll
    for (int nb = 0; nb < 2; ++nb) {
        l_i[nb] += __shfl_xor(l_i[nb], 16, 64);
        l_i[nb] += __shfl_xor(l_i[nb], 32, 64);
    }
    // unnormalized y partial (fp16) + (m,l) stats (m in base-2)
    half_t* yp = ypart + ((size_t)ksb * BN_ + (size_t)b * N_) * D_;
#pragma unroll
    for (int mb = 0; mb < 2; ++mb)
#pragma unroll
        for (int dn = 0; dn < 8; ++dn)
#pragma unroll
            for (int r = 0; r < 4; ++r)
                yp[(size_t)(q0 + w * 32 + mb * 16 + lq * 4 + r) * D_ + dn * 16 + lm] =
                    (half_t)yacc[mb][dn][r];
    if (lq == 0) {
#pragma unroll
        for (int nb = 0; nb < 2; ++nb) {
            const int row = q0 + w * 32 + nb * 16 + lm;
            mstat[(size_t)ksb * BN_ + (size_t)b * N_ + row] = m_i[nb];
            lstat[(size_t)ksb * BN_ + (size_t)b * N_ + row] = l_i[nb];
        }
    }
}

// ---- final (MFMA): merge nsplit partials (base-2 stats), z = x + y @ Wf ----
// grid (BN_/128, 2), block 256. LDS = 40,960 B.
__global__ __launch_bounds__(256) void final_kernel(
    const half_t* __restrict__ ypart, const float* __restrict__ mstat,
    const float* __restrict__ lstat, const float* __restrict__ x,
    const half_t* __restrict__ WfT, float* __restrict__ out, int nsplit)
{
    const int tid = threadIdx.x;
    const int lane = tid & 63;
    const int w = tid >> 6;
    const int lm = lane & 15;
    const int lq = lane >> 4;
    const int r0 = blockIdx.x * 128;
    const int c0 = blockIdx.y * 128;

    __shared__ half_t Ys[128][72];
    __shared__ half_t Wfs[128][72];
    __shared__ float scl[MAXSPLIT][128];

    if (tid < 128) {
        const int row = r0 + tid;
        float mv[MAXSPLIT], lv[MAXSPLIT];
        float Mx = -1e30f;
        for (int s = 0; s < nsplit; ++s) {
            mv[s] = mstat[(size_t)s * BN_ + row];
            lv[s] = lstat[(size_t)s * BN_ + row];
            Mx = fmaxf(Mx, mv[s]);
        }
        float lsum = 0.f;
        float wv[MAXSPLIT];
        for (int s = 0; s < nsplit; ++s) { wv[s] = exp2f(mv[s] - Mx); lsum += wv[s] * lv[s]; }
        const float inv = 1.f / lsum;
        for (int s = 0; s < nsplit; ++s) scl[s][tid] = wv[s] * inv;
    }
    __syncthreads();

    f32x4 acc[2][8];
#pragma unroll
    for (int rb = 0; rb < 2; ++rb)
#pragma unroll
        for (int nb = 0; nb < 8; ++nb)
#pragma unroll
            for (int r = 0; r < 4; ++r) acc[rb][nb][r] = 0.f;

    const int sr = tid >> 1;
    const int dd = (tid & 1) * 32;

    for (int kc = 0; kc < 2; ++kc) {
        {
            const size_t yb = (size_t)(r0 + sr) * D_ + kc * 64 + dd;
            half8 o[4];
#pragma unroll
            for (int q = 0; q < 4; ++q) {
                float m[8];
#pragma unroll
                for (int j = 0; j < 8; ++j) m[j] = 0.f;
                for (int s = 0; s < nsplit; ++s) {
                    const float ss = scl[s][sr];
                    half8 yv = *(const half8*)&ypart[(size_t)s * BN_ * D_ + yb + q * 8];
#pragma unroll
                    for (int j = 0; j < 8; ++j) m[j] += ss * (float)yv[j];
                }
#pragma unroll
                for (int j = 0; j < 8; ++j) o[q][j] = (half_t)m[j];
            }
#pragma unroll
            for (int q = 0; q < 4; ++q) *(half8*)&Ys[sr][dd + q * 8] = o[q];
            const half_t* wf = WfT + (size_t)(c0 + sr) * D_ + kc * 64 + dd;
#pragma unroll
            for (int q = 0; q < 4; ++q)
                *(half8*)&Wfs[sr][dd + q * 8] = *(const half8*)&wf[q * 8];
        }
        __syncthreads();

        half8 af[2][2];
#pragma unroll
        for (int rb = 0; rb < 2; ++rb)
#pragma unroll
            for (int k2 = 0; k2 < 2; ++k2)
                af[rb][k2] = *(const half8*)&Ys[w * 32 + rb * 16 + lm][k2 * 32 + lq * 8];
#pragma unroll
        for (int nb = 0; nb < 8; ++nb) {
#pragma unroll
            for (int k2 = 0; k2 < 2; ++k2) {
                half8 bf = *(const half8*)&Wfs[nb * 16 + lm][k2 * 32 + lq * 8];
                acc[0][nb] = MFMA16x16x32(af[0][k2], bf, acc[0][nb]);
                acc[1][nb] = MFMA16x16x32(af[1][k2], bf, acc[1][nb]);
            }
        }
        __syncthreads();
    }
#pragma unroll
    for (int rb = 0; rb < 2; ++rb)
#pragma unroll
        for (int nb = 0; nb < 8; ++nb)
#pragma unroll
            for (int r = 0; r < 4; ++r) {
                const int row = r0 + w * 32 + rb * 16 + lq * 4 + r;
                const int col = c0 + nb * 16 + lm;
                out[(size_t)row * C_ + col] =
                    acc[rb][nb][r] + x[(size_t)row * C_ + col];
            }
}

extern "C" void kernel_launch(void* const* d_in, const int* in_sizes, int n_in,
                              void* d_out, int out_size, void* d_ws, size_t ws_size,
                              hipStream_t stream)
{
    const float* x  = (const float*)d_in[0];
    const float* Wt = (const float*)d_in[1];
    const float* Wp = (const float*)d_in[2];
    const float* Wg = (const float*)d_in[3];
    const float* Wf = (const float*)d_in[4];
    float* out = (float*)d_out;

    const size_t SEG = (size_t)BN_ * D_;   // 2,097,152 fp32 words
    const size_t words8 = 3 * SEG / 2 + 8 * SEG / 2 + (size_t)2 * 8 * BN_ + 65536;
    const int nsplit = (ws_size >= words8 * sizeof(float)) ? 8 : 4;

    float* ws     = (float*)d_ws;
    half_t* theta = (half_t*)ws;
    half_t* pphi  = (half_t*)(ws + SEG / 2);
    half_t* pgT   = (half_t*)(ws + SEG);
    half_t* ypart = (half_t*)(ws + 3 * SEG / 2);
    float* mstat  = ws + 3 * SEG / 2 + (size_t)nsplit * SEG / 2;
    float* lstat  = mstat + (size_t)nsplit * BN_;
    half_t* WT_hi = (half_t*)(lstat + (size_t)nsplit * BN_);
    half_t* WfT   = WT_hi + 3 * 32768;

    prep_kernel<<<dim3(128, 4), 256, 0, stream>>>(Wt, Wp, Wg, Wf, WT_hi, WfT);
    proj_kernel<<<dim3(BN_ / 64, 3), 256, 0, stream>>>(x, WT_hi, theta, pphi, pgT);
    attn_kernel<<<dim3(N_ / 128, nsplit, B_), 256, 0, stream>>>(
        theta, pphi, pgT, ypart, mstat, lstat, nsplit);
    final_kernel<<<dim3(BN_ / 128, 2), 256, 0, stream>>>(
        ypart, mstat, lstat, x, WfT, out, nsplit);
}

// Round 14
// 185.918 us; speedup vs baseline: 1.3218x; 1.0001x over previous
//
#include <hip/hip_runtime.h>

#define B_  4
#define N_  4096
#define C_  256
#define D_  128
#define M_  4095
#define BN_ (B_ * N_)
#define KSPLIT 4

typedef _Float16 half_t;
typedef __attribute__((ext_vector_type(8))) _Float16 half8;
typedef __attribute__((ext_vector_type(4))) _Float16 half4;
typedef __attribute__((ext_vector_type(4))) float f32x4;

#define MFMA16x16x32(A, B, C) __builtin_amdgcn_mfma_f32_16x16x32_f16(A, B, C, 0, 0, 0)
#define LOG2E 1.44269504088896f

// ---- prep: weights into B-fragment layouts (runs once, tiny) ----
__global__ __launch_bounds__(256) void prep_kernel(
    const float* __restrict__ Wt, const float* __restrict__ Wp,
    const float* __restrict__ Wg, const float* __restrict__ Wf,
    half_t* __restrict__ WT_hi, half_t* __restrict__ WfT)
{
    const int idx = blockIdx.x * 256 + threadIdx.x;   // 0..32767
    const int wsel = blockIdx.y;
    if (wsel < 3) {
        const float* __restrict__ W = (wsel == 0) ? Wt : (wsel == 1) ? Wp : Wg;
        const int d = idx >> 8, c = idx & 255;
        WT_hi[(size_t)wsel * 32768 + idx] = (half_t)W[(size_t)c * D_ + d];
    } else {
        const int c = idx >> 7, d = idx & 127;
        WfT[idx] = (half_t)Wf[(size_t)d * C_ + c];
    }
}

// ---- proj: x staged ONCE (fp16 LDS), 3 sequential GEMMs + fused pool ----
// grid BN_/64 = 256 blocks (1/CU), block 256. LDS = 62,464 B (2 blocks fit).
__global__ __launch_bounds__(256) void proj_kernel(
    const float* __restrict__ x, const half_t* __restrict__ WT_hi,
    half_t* __restrict__ theta, half_t* __restrict__ pphi,
    half_t* __restrict__ pgT)
{
    const int tid = threadIdx.x;
    const int lane = tid & 63;
    const int w = tid >> 6;
    const int lm = lane & 15;
    const int lq = lane >> 4;
    const int r0 = blockIdx.x * 64;

    __shared__ __align__(16) unsigned char lds_raw[62464];
    half_t (*Xb)[264] = (half_t (*)[264])(lds_raw);             // 33,792 B
    half_t (*Wc)[40]  = (half_t (*)[40])(lds_raw + 33792);      // 10,240 B
    half_t (*LsT)[72] = (half_t (*)[72])(lds_raw + 44032);      // 18,432 B

    {   // stage x (64 rows x 256 cols) fp32 -> fp16, once
        const int row = tid >> 2;
        const int cb = (tid & 3) * 64;
        const float* xs = x + (size_t)(r0 + row) * C_ + cb;
#pragma unroll
        for (int j = 0; j < 4; ++j) {
            float4 v0 = *(const float4*)&xs[j * 16];
            float4 v1 = *(const float4*)&xs[j * 16 + 4];
            float4 v2 = *(const float4*)&xs[j * 16 + 8];
            float4 v3 = *(const float4*)&xs[j * 16 + 12];
            half8 h0, h1;
            h0[0]=(half_t)v0.x; h0[1]=(half_t)v0.y; h0[2]=(half_t)v0.z; h0[3]=(half_t)v0.w;
            h0[4]=(half_t)v1.x; h0[5]=(half_t)v1.y; h0[6]=(half_t)v1.z; h0[7]=(half_t)v1.w;
            h1[0]=(half_t)v2.x; h1[1]=(half_t)v2.y; h1[2]=(half_t)v2.z; h1[3]=(half_t)v2.w;
            h1[4]=(half_t)v3.x; h1[5]=(half_t)v3.y; h1[6]=(half_t)v3.z; h1[7]=(half_t)v3.w;
            *(half8*)&Xb[row][cb + j * 16]     = h0;
            *(half8*)&Xb[row][cb + j * 16 + 8] = h1;
        }
    }

    const int wr = tid >> 1, wc = (tid & 1) * 16;

    for (int which = 0; which < 3; ++which) {
        const half_t* __restrict__ Wg_ = WT_hi + (size_t)which * 32768;
        f32x4 acc[8];
#pragma unroll
        for (int nb = 0; nb < 8; ++nb)
#pragma unroll
            for (int r = 0; r < 4; ++r) acc[nb][r] = 0.f;

        for (int kc = 0; kc < 8; ++kc) {
            __syncthreads();   // covers x-stage (first iter) and prev Wc reads
            {
                const half_t* wsrc = Wg_ + (size_t)wr * 256 + kc * 32 + wc;
                *(half8*)&Wc[wr][wc]     = *(const half8*)&wsrc[0];
                *(half8*)&Wc[wr][wc + 8] = *(const half8*)&wsrc[8];
            }
            __syncthreads();

            half8 ah = *(const half8*)&Xb[w * 16 + lm][kc * 32 + lq * 8];
#pragma unroll
            for (int nb = 0; nb < 8; ++nb) {
                half8 bh = *(const half8*)&Wc[nb * 16 + lm][lq * 8];
                acc[nb] = MFMA16x16x32(ah, bh, acc[nb]);
            }
        }

        if (which == 0) {   // theta: scale by log2e, fp16 store (base-2 QK)
#pragma unroll
            for (int nb = 0; nb < 8; ++nb)
#pragma unroll
                for (int r = 0; r < 4; ++r)
                    theta[(size_t)(r0 + w * 16 + lq * 4 + r) * D_ + nb * 16 + lm] =
                        (half_t)(acc[nb][r] * LOG2E);
            continue;       // next which's loop-top barrier orders everything
        }

        // pool path: acc -> LsT[d][m] fp16, halo row, pool, store
        // (LsT is a dedicated region; prev pooled reads protected by loop-top
        //  barrier of this which's kc-loop)
#pragma unroll
        for (int nb = 0; nb < 8; ++nb) {
            const int d = nb * 16 + lm;
            const int m = w * 16 + lq * 4;
            half4 pk;
#pragma unroll
            for (int r = 0; r < 4; ++r) pk[r] = (half_t)acc[nb][r];
            *(half4*)&LsT[d][m] = pk;
        }
        if (tid < 128) {    // halo: projected row r0+64 (clamped at batch end)
            int rh = r0 + 64;
            if ((rh & (N_ - 1)) == 0) rh = r0 + 63;
            const float* xrow = x + (size_t)rh * C_;
            const half_t* wrow = Wg_ + (size_t)tid * 256;
            float s = 0.f;
#pragma unroll
            for (int c8 = 0; c8 < 32; ++c8) {
                half8 h = *(const half8*)&wrow[c8 * 8];
                float4 xa = *(const float4*)&xrow[c8 * 8];
                float4 xb = *(const float4*)&xrow[c8 * 8 + 4];
                s += xa.x * (float)h[0] + xa.y * (float)h[1]
                   + xa.z * (float)h[2] + xa.w * (float)h[3]
                   + xb.x * (float)h[4] + xb.y * (float)h[5]
                   + xb.z * (float)h[6] + xb.w * (float)h[7];
            }
            LsT[tid][64] = (half_t)s;
        }
        __syncthreads();

        if (which == 1) {   // pooled phi -> pphi[m][d]
            const int m = tid >> 2, dh = (tid & 3) * 32;
            half8 o[4];
#pragma unroll
            for (int j = 0; j < 32; ++j) {
                float v0 = (float)LsT[dh + j][m];
                float v1 = (float)LsT[dh + j][m + 1];
                o[j >> 3][j & 7] = (half_t)fmaxf(v0, v1);
            }
            half8* dst = (half8*)&pphi[(size_t)(r0 + m) * D_ + dh];
#pragma unroll
            for (int j = 0; j < 4; ++j) dst[j] = o[j];
        } else {            // pooled g -> pgT[b][d][m]
            const int d = tid >> 1, mh = (tid & 1) * 32;
            const int b = r0 / N_, m0 = r0 & (N_ - 1);
            half8 in[4];
#pragma unroll
            for (int j = 0; j < 4; ++j) in[j] = *(const half8*)&LsT[d][mh + j * 8];
            const half_t ext = LsT[d][mh + 32];
            half8 o[4];
#pragma unroll
            for (int j = 0; j < 32; ++j) {
                float v0 = (float)in[j >> 3][j & 7];
                float v1 = (j == 31) ? (float)ext : (float)in[(j + 1) >> 3][(j + 1) & 7];
                o[j >> 3][j & 7] = (half_t)fmaxf(v0, v1);
            }
            half8* dst = (half8*)&pgT[((size_t)b * D_ + d) * N_ + m0 + mh];
#pragma unroll
            for (int j = 0; j < 4; ++j) dst[j] = o[j];
        }
    }
}

// ---------------- MFMA flash attention (r11 config + alpha-skip) ----------
// grid (N_/128, KSPLIT, B_) = 512 blocks, 256 thr. LDS = 54,272 B.
__global__ __launch_bounds__(256, 2) void attn_kernel(
    const half_t* __restrict__ theta, const half_t* __restrict__ pphi,
    const half_t* __restrict__ pgT, half_t* __restrict__ ypart,
    float* __restrict__ mstat, float* __restrict__ lstat)
{
    const int tid = threadIdx.x;
    const int lane = tid & 63;
    const int w = tid >> 6;
    const int lm = lane & 15;
    const int lq = lane >> 4;      // 0..3
    const int qt = blockIdx.x, ksb = blockIdx.y, b = blockIdx.z;
    const int q0 = qt * 128;
    const int kt0 = ksb * 16, kt1 = kt0 + 16;

    __shared__ half_t Ks[64][136];   // K tile [key][d]        17,408 B
    __shared__ half_t Gts[128][72];  // G tile [d][key]        18,432 B
    __shared__ half_t Ps[128][72];   // P [q][key] wave-private 18,432 B

    half8 qh[2][4];
#pragma unroll
    for (int nb = 0; nb < 2; ++nb) {
        const half_t* tr_ = theta + ((size_t)b * N_ + q0 + w * 32 + nb * 16 + lm) * D_;
#pragma unroll
        for (int k4 = 0; k4 < 4; ++k4)
            qh[nb][k4] = *(const half8*)(tr_ + k4 * 32 + lq * 8);
    }

    float m_i[2] = {-1e30f, -1e30f};
    float l_i[2] = {0.f, 0.f};      // per-quad partial; cross-quad sum deferred
    f32x4 yacc[2][8];
#pragma unroll
    for (int mb = 0; mb < 2; ++mb)
#pragma unroll
        for (int dn = 0; dn < 8; ++dn)
#pragma unroll
            for (int r = 0; r < 4; ++r) yacc[mb][dn][r] = 0.f;

    for (int kt = kt0; kt < kt1; ++kt) {
        const int k0 = kt * 64;
        __syncthreads();
        {   // stage K [key][d] and G^T [d][key] cooperatively (coalesced)
            const int key = tid >> 2, ch = (tid & 3);
            const float4* src = (const float4*)(pphi +
                ((size_t)b * N_ + k0 + key) * D_ + ch * 32);
            float4 a0 = src[0], a1 = src[1], a2 = src[2], a3 = src[3];
            float4* dst = (float4*)&Ks[key][ch * 32];
            dst[0] = a0; dst[1] = a1; dst[2] = a2; dst[3] = a3;
            const int d = tid >> 1, kh = (tid & 1);
            const float4* gs = (const float4*)(pgT +
                ((size_t)b * D_ + d) * N_ + k0 + kh * 32);
            float4 g0 = gs[0], g1 = gs[1], g2 = gs[2], g3 = gs[3];
            float4* gd = (float4*)&Gts[d][kh * 32];
            gd[0] = g0; gd[1] = g1; gd[2] = g2; gd[3] = g3;
        }
        __syncthreads();

        // QK^T transposed: S^T[key][q]; A = K (LDS), B = Q (regs)
        f32x4 sc[4][2];
#pragma unroll
        for (int kb = 0; kb < 4; ++kb)
#pragma unroll
            for (int nb = 0; nb < 2; ++nb)
#pragma unroll
                for (int r = 0; r < 4; ++r) sc[kb][nb][r] = 0.f;
#pragma unroll
        for (int kb = 0; kb < 4; ++kb) {
#pragma unroll
            for (int k4 = 0; k4 < 4; ++k4) {
                half8 kf = *(const half8*)&Ks[kb * 16 + lm][k4 * 32 + lq * 8];
#pragma unroll
                for (int nb = 0; nb < 2; ++nb)
                    sc[kb][nb] = MFMA16x16x32(kf, qh[nb][k4], sc[kb][nb]);
            }
        }
        // mask padded key 4095 (only last tile of last split)
        if (k0 + 64 > M_) {
#pragma unroll
            for (int kb = 0; kb < 4; ++kb)
#pragma unroll
                for (int r = 0; r < 4; ++r)
                    if (k0 + kb * 16 + lq * 4 + r >= M_) {
                        sc[kb][0][r] = -1e30f; sc[kb][1][r] = -1e30f;
                    }
        }
        // online softmax (base-2); m common across quads, l per-quad partial
        float alpha[2];
#pragma unroll
        for (int nb = 0; nb < 2; ++nb) {
            float mt = -1e30f;
#pragma unroll
            for (int kb = 0; kb < 4; ++kb)
#pragma unroll
                for (int r = 0; r < 4; ++r) mt = fmaxf(mt, sc[kb][nb][r]);
            mt = fmaxf(mt, __shfl_xor(mt, 16, 64));
            mt = fmaxf(mt, __shfl_xor(mt, 32, 64));
            const float mnew = fmaxf(m_i[nb], mt);
            alpha[nb] = exp2f(m_i[nb] - mnew);
            m_i[nb] = mnew;
            float rs = 0.f;
#pragma unroll
            for (int kb = 0; kb < 4; ++kb)
#pragma unroll
                for (int r = 0; r < 4; ++r) {
                    float p = exp2f(sc[kb][nb][r] - mnew);
                    sc[kb][nb][r] = p;
                    rs += p;
                }
            l_i[nb] = l_i[nb] * alpha[nb] + rs;
            // P store: 4 consecutive keys at fixed q -> one b64 per (kb)
#pragma unroll
            for (int kb = 0; kb < 4; ++kb) {
                half4 pk;
#pragma unroll
                for (int r = 0; r < 4; ++r) pk[r] = (half_t)sc[kb][nb][r];
                *(half4*)&Ps[w * 32 + nb * 16 + lm][kb * 16 + lq * 4] = pk;
            }
        }
        // alpha-skip: alpha == 1.0 exactly when this tile set no new max.
        // Skip the transpose shuffles + 64 rescale muls in that (common) case.
        const int need = (alpha[0] != 1.0f) || (alpha[1] != 1.0f);
        if (__any(need)) {
            float alpha_t[2][4];
#pragma unroll
            for (int mb = 0; mb < 2; ++mb)
#pragma unroll
                for (int r = 0; r < 4; ++r)
                    alpha_t[mb][r] = __shfl(alpha[mb], lq * 4 + r, 16);
#pragma unroll
            for (int mb = 0; mb < 2; ++mb)
#pragma unroll
                for (int dn = 0; dn < 8; ++dn)
#pragma unroll
                    for (int r = 0; r < 4; ++r) yacc[mb][dn][r] *= alpha_t[mb][r];
        }
        // PV: A = P (LDS, wave-private rows), B = G^T (LDS)
        half8 pf[2][2];
#pragma unroll
        for (int mb = 0; mb < 2; ++mb)
#pragma unroll
            for (int k2 = 0; k2 < 2; ++k2)
                pf[mb][k2] = *(const half8*)&Ps[w * 32 + mb * 16 + lm][k2 * 32 + lq * 8];
#pragma unroll
        for (int dn = 0; dn < 8; ++dn) {
#pragma unroll
            for (int k2 = 0; k2 < 2; ++k2) {
                half8 gf = *(const half8*)&Gts[dn * 16 + lm][k2 * 32 + lq * 8];
                yacc[0][dn] = MFMA16x16x32(pf[0][k2], gf, yacc[0][dn]);
                yacc[1][dn] = MFMA16x16x32(pf[1][k2], gf, yacc[1][dn]);
            }
        }
    }

    // epilogue: finish l (cross-quad sum, deferred)
#pragma unroll
    for (int nb = 0; nb < 2; ++nb) {
        l_i[nb] += __shfl_xor(l_i[nb], 16, 64);
        l_i[nb] += __shfl_xor(l_i[nb], 32, 64);
    }
    half_t* yp = ypart + ((size_t)ksb * BN_ + (size_t)b * N_) * D_;
#pragma unroll
    for (int mb = 0; mb < 2; ++mb)
#pragma unroll
        for (int dn = 0; dn < 8; ++dn)
#pragma unroll
            for (int r = 0; r < 4; ++r)
                yp[(size_t)(q0 + w * 32 + mb * 16 + lq * 4 + r) * D_ + dn * 16 + lm] =
                    (half_t)yacc[mb][dn][r];
    if (lq == 0) {
#pragma unroll
        for (int nb = 0; nb < 2; ++nb) {
            const int row = q0 + w * 32 + nb * 16 + lm;
            mstat[(size_t)ksb * BN_ + (size_t)b * N_ + row] = m_i[nb];
            lstat[(size_t)ksb * BN_ + (size_t)b * N_ + row] = l_i[nb];
        }
    }
}

// ---- final (MFMA): merge 4 partials (base-2 stats), z = x + y @ Wf ----
// grid (BN_/128, 2), block 256. LDS = 38,912 B.
__global__ __launch_bounds__(256) void final_kernel(
    const half_t* __restrict__ ypart, const float* __restrict__ mstat,
    const float* __restrict__ lstat, const float* __restrict__ x,
    const half_t* __restrict__ WfT, float* __restrict__ out)
{
    const int tid = threadIdx.x;
    const int lane = tid & 63;
    const int w = tid >> 6;
    const int lm = lane & 15;
    const int lq = lane >> 4;
    const int r0 = blockIdx.x * 128;
    const int c0 = blockIdx.y * 128;

    __shared__ half_t Ys[128][72];
    __shared__ half_t Wfs[128][72];
    __shared__ float scl[KSPLIT][128];

    if (tid < 128) {
        const int row = r0 + tid;
        float mv[KSPLIT], lv[KSPLIT], wv[KSPLIT];
        float Mx = -1e30f;
#pragma unroll
        for (int s = 0; s < KSPLIT; ++s) {
            mv[s] = mstat[(size_t)s * BN_ + row];
            lv[s] = lstat[(size_t)s * BN_ + row];
            Mx = fmaxf(Mx, mv[s]);
        }
        float lsum = 0.f;
#pragma unroll
        for (int s = 0; s < KSPLIT; ++s) { wv[s] = exp2f(mv[s] - Mx); lsum += wv[s] * lv[s]; }
        const float inv = 1.f / lsum;
#pragma unroll
        for (int s = 0; s < KSPLIT; ++s) scl[s][tid] = wv[s] * inv;
    }
    __syncthreads();

    f32x4 acc[2][8];
#pragma unroll
    for (int rb = 0; rb < 2; ++rb)
#pragma unroll
        for (int nb = 0; nb < 8; ++nb)
#pragma unroll
            for (int r = 0; r < 4; ++r) acc[rb][nb][r] = 0.f;

    const int sr = tid >> 1;
    const int dd = (tid & 1) * 32;

    for (int kc = 0; kc < 2; ++kc) {
        {
            float ss[KSPLIT];
#pragma unroll
            for (int s = 0; s < KSPLIT; ++s) ss[s] = scl[s][sr];
            const size_t yb = (size_t)(r0 + sr) * D_ + kc * 64 + dd;
            half8 o[4];
#pragma unroll
            for (int q = 0; q < 4; ++q) {
                float m[8];
#pragma unroll
                for (int j = 0; j < 8; ++j) m[j] = 0.f;
#pragma unroll
                for (int s = 0; s < KSPLIT; ++s) {
                    half8 yv = *(const half8*)&ypart[(size_t)s * BN_ * D_ + yb + q * 8];
#pragma unroll
                    for (int j = 0; j < 8; ++j) m[j] += ss[s] * (float)yv[j];
                }
#pragma unroll
                for (int j = 0; j < 8; ++j) o[q][j] = (half_t)m[j];
            }
#pragma unroll
            for (int q = 0; q < 4; ++q) *(half8*)&Ys[sr][dd + q * 8] = o[q];
            const half_t* wf = WfT + (size_t)(c0 + sr) * D_ + kc * 64 + dd;
#pragma unroll
            for (int q = 0; q < 4; ++q)
                *(half8*)&Wfs[sr][dd + q * 8] = *(const half8*)&wf[q * 8];
        }
        __syncthreads();

        half8 af[2][2];
#pragma unroll
        for (int rb = 0; rb < 2; ++rb)
#pragma unroll
            for (int k2 = 0; k2 < 2; ++k2)
                af[rb][k2] = *(const half8*)&Ys[w * 32 + rb * 16 + lm][k2 * 32 + lq * 8];
#pragma unroll
        for (int nb = 0; nb < 8; ++nb) {
#pragma unroll
            for (int k2 = 0; k2 < 2; ++k2) {
                half8 bf = *(const half8*)&Wfs[nb * 16 + lm][k2 * 32 + lq * 8];
                acc[0][nb] = MFMA16x16x32(af[0][k2], bf, acc[0][nb]);
                acc[1][nb] = MFMA16x16x32(af[1][k2], bf, acc[1][nb]);
            }
        }
        __syncthreads();
    }
#pragma unroll
    for (int rb = 0; rb < 2; ++rb)
#pragma unroll
        for (int nb = 0; nb < 8; ++nb)
#pragma unroll
            for (int r = 0; r < 4; ++r) {
                const int row = r0 + w * 32 + rb * 16 + lq * 4 + r;
                const int col = c0 + nb * 16 + lm;
                out[(size_t)row * C_ + col] =
                    acc[rb][nb][r] + x[(size_t)row * C_ + col];
            }
}

extern "C" void kernel_launch(void* const* d_in, const int* in_sizes, int n_in,
                              void* d_out, int out_size, void* d_ws, size_t ws_size,
                              hipStream_t stream)
{
    const float* x  = (const float*)d_in[0];
    const float* Wt = (const float*)d_in[1];
    const float* Wp = (const float*)d_in[2];
    const float* Wg = (const float*)d_in[3];
    const float* Wf = (const float*)d_in[4];
    float* out = (float*)d_out;

    // ws (fp32 words, SEG = BN_*D_): theta f16 | pphi f16 | pgT f16 |
    // ypart f16 x4 | mstat | lstat | WT_hi | WfT  (~30 MB)
    const size_t SEG = (size_t)BN_ * D_;   // 2,097,152
    float* ws     = (float*)d_ws;
    half_t* theta = (half_t*)ws;
    half_t* pphi  = (half_t*)(ws + SEG / 2);
    half_t* pgT   = (half_t*)(ws + SEG);
    half_t* ypart = (half_t*)(ws + 3 * SEG / 2);
    float* mstat  = ws + 3 * SEG / 2 + (size_t)KSPLIT * SEG / 2;
    float* lstat  = mstat + (size_t)KSPLIT * BN_;
    half_t* WT_hi = (half_t*)(lstat + (size_t)KSPLIT * BN_);
    half_t* WfT   = WT_hi + 3 * 32768;

    prep_kernel<<<dim3(128, 4), 256, 0, stream>>>(Wt, Wp, Wg, Wf, WT_hi, WfT);
    proj_kernel<<<dim3(BN_ / 64), 256, 0, stream>>>(x, WT_hi, theta, pphi, pgT);
    attn_kernel<<<dim3(N_ / 128, KSPLIT, B_), 256, 0, stream>>>(
        theta, pphi, pgT, ypart, mstat, lstat);
    final_kernel<<<dim3(BN_ / 128, 2), 256, 0, stream>>>(
        ypart, mstat, lstat, x, WfT, out);
}

// Round 15
// 176.585 us; speedup vs baseline: 1.3917x; 1.0529x over previous
//
#include <hip/hip_runtime.h>

#define B_  4
#define N_  4096
#define C_  256
#define D_  128
#define M_  4095
#define BN_ (B_ * N_)
#define KSPLIT 4

typedef _Float16 half_t;
typedef __attribute__((ext_vector_type(8))) _Float16 half8;
typedef __attribute__((ext_vector_type(4))) _Float16 half4;
typedef __attribute__((ext_vector_type(4))) float f32x4;

#define MFMA16x16x32(A, B, C) __builtin_amdgcn_mfma_f32_16x16x32_f16(A, B, C, 0, 0, 0)
#define LOG2E 1.44269504088896f

// ---- prep: weights into B-fragment layouts (runs once, tiny) ----
__global__ __launch_bounds__(256) void prep_kernel(
    const float* __restrict__ Wt, const float* __restrict__ Wp,
    const float* __restrict__ Wg, const float* __restrict__ Wf,
    half_t* __restrict__ WT_hi, half_t* __restrict__ WfT)
{
    const int idx = blockIdx.x * 256 + threadIdx.x;   // 0..32767
    const int wsel = blockIdx.y;
    if (wsel < 3) {
        const float* __restrict__ W = (wsel == 0) ? Wt : (wsel == 1) ? Wp : Wg;
        const int d = idx >> 8, c = idx & 255;
        WT_hi[(size_t)wsel * 32768 + idx] = (half_t)W[(size_t)c * D_ + d];
    } else {
        const int c = idx >> 7, d = idx & 127;
        WfT[idx] = (half_t)Wf[(size_t)d * C_ + c];
    }
}

// ---- proj (single-fp16 MFMA) + FUSED maxpool/transpose ----
// r11-verified: grid (BN_/64, 3) = 768 blocks (3/CU), block 256. LDS 18,432 B.
__global__ __launch_bounds__(256) void proj_kernel(
    const float* __restrict__ x, const half_t* __restrict__ WT_hi,
    half_t* __restrict__ theta, half_t* __restrict__ pphi,
    half_t* __restrict__ pgT)
{
    const int tid = threadIdx.x;
    const int lane = tid & 63;
    const int w = tid >> 6;
    const int lm = lane & 15;
    const int lq = lane >> 4;
    const int r0 = blockIdx.x * 64;
    const int which = blockIdx.y;
    const half_t* __restrict__ Wg_ = WT_hi + (size_t)which * 32768;

    __shared__ __align__(16) unsigned char lds_raw[18432];
    half_t (*Xh)[40]  = (half_t (*)[40])(lds_raw);
    half_t (*Whl)[40] = (half_t (*)[40])(lds_raw + 5120);

    f32x4 acc[8];
#pragma unroll
    for (int nb = 0; nb < 8; ++nb)
#pragma unroll
        for (int r = 0; r < 4; ++r) acc[nb][r] = 0.f;

    const int xr = tid >> 2, xc = (tid & 3) * 8;
    const int wr = tid >> 1, wc = (tid & 1) * 16;

    for (int kc = 0; kc < 8; ++kc) {
        __syncthreads();
        {
            const float* xs = x + (size_t)(r0 + xr) * C_ + kc * 32 + xc;
            float4 v0 = *(const float4*)&xs[0], v1 = *(const float4*)&xs[4];
            half8 hi;
            hi[0] = (half_t)v0.x; hi[1] = (half_t)v0.y;
            hi[2] = (half_t)v0.z; hi[3] = (half_t)v0.w;
            hi[4] = (half_t)v1.x; hi[5] = (half_t)v1.y;
            hi[6] = (half_t)v1.z; hi[7] = (half_t)v1.w;
            *(half8*)&Xh[xr][xc] = hi;
            const half_t* wsrc = Wg_ + (size_t)wr * 256 + kc * 32 + wc;
            *(half8*)&Whl[wr][wc]     = *(const half8*)&wsrc[0];
            *(half8*)&Whl[wr][wc + 8] = *(const half8*)&wsrc[8];
        }
        __syncthreads();

        half8 ah = *(const half8*)&Xh[w * 16 + lm][lq * 8];
#pragma unroll
        for (int nb = 0; nb < 8; ++nb) {
            half8 bh = *(const half8*)&Whl[nb * 16 + lm][lq * 8];
            acc[nb] = MFMA16x16x32(ah, bh, acc[nb]);
        }
    }

    if (which == 0) {   // theta: scale by log2e, store fp16 (QK runs in base-2)
#pragma unroll
        for (int nb = 0; nb < 8; ++nb)
#pragma unroll
            for (int r = 0; r < 4; ++r)
                theta[(size_t)(r0 + w * 16 + lq * 4 + r) * D_ + nb * 16 + lm] =
                    (half_t)(acc[nb][r] * LOG2E);
        return;
    }

    __syncthreads();
    half_t (*LsT)[72] = (half_t (*)[72])(lds_raw);
#pragma unroll
    for (int nb = 0; nb < 8; ++nb) {
        const int d = nb * 16 + lm;
        const int m = w * 16 + lq * 4;
        half4 pk;
#pragma unroll
        for (int r = 0; r < 4; ++r) pk[r] = (half_t)acc[nb][r];
        *(half4*)&LsT[d][m] = pk;
    }
    if (tid < 128) {   // halo: projected row r0+64 (clamped at batch boundary)
        int rh = r0 + 64;
        if ((rh & (N_ - 1)) == 0) rh = r0 + 63;
        const float* xrow = x + (size_t)rh * C_;
        const half_t* wrow = Wg_ + (size_t)tid * 256;
        float s = 0.f;
#pragma unroll
        for (int c8 = 0; c8 < 32; ++c8) {
            half8 h = *(const half8*)&wrow[c8 * 8];
            float4 xa = *(const float4*)&xrow[c8 * 8];
            float4 xb = *(const float4*)&xrow[c8 * 8 + 4];
            s += xa.x * (float)h[0] + xa.y * (float)h[1]
               + xa.z * (float)h[2] + xa.w * (float)h[3]
               + xb.x * (float)h[4] + xb.y * (float)h[5]
               + xb.z * (float)h[6] + xb.w * (float)h[7];
        }
        LsT[tid][64] = (half_t)s;
    }
    __syncthreads();

    if (which == 1) {   // pooled phi -> pphi[m][d]
        const int m = tid >> 2, dh = (tid & 3) * 32;
        half8 o[4];
#pragma unroll
        for (int j = 0; j < 32; ++j) {
            float v0 = (float)LsT[dh + j][m];
            float v1 = (float)LsT[dh + j][m + 1];
            o[j >> 3][j & 7] = (half_t)fmaxf(v0, v1);
        }
        half8* dst = (half8*)&pphi[(size_t)(r0 + m) * D_ + dh];
#pragma unroll
        for (int j = 0; j < 4; ++j) dst[j] = o[j];
    } else {            // pooled g -> pgT[b][d][m]
        const int d = tid >> 1, mh = (tid & 1) * 32;
        const int b = r0 / N_, m0 = r0 & (N_ - 1);
        half8 in[4];
#pragma unroll
        for (int j = 0; j < 4; ++j) in[j] = *(const half8*)&LsT[d][mh + j * 8];
        const half_t ext = LsT[d][mh + 32];
        half8 o[4];
#pragma unroll
        for (int j = 0; j < 32; ++j) {
            float v0 = (float)in[j >> 3][j & 7];
            float v1 = (j == 31) ? (float)ext : (float)in[(j + 1) >> 3][(j + 1) & 7];
            o[j >> 3][j & 7] = (half_t)fmaxf(v0, v1);
        }
        half8* dst = (half8*)&pgT[((size_t)b * D_ + d) * N_ + m0 + mh];
#pragma unroll
        for (int j = 0; j < 4; ++j) dst[j] = o[j];
    }
}

// ---------------- MFMA flash attention (r11-verified configuration) --------
// grid (N_/128, KSPLIT, B_) = 512 blocks, 256 thr. LDS = 54,272 B.
__global__ __launch_bounds__(256, 2) void attn_kernel(
    const half_t* __restrict__ theta, const half_t* __restrict__ pphi,
    const half_t* __restrict__ pgT, half_t* __restrict__ ypart,
    float* __restrict__ mstat, float* __restrict__ lstat)
{
    const int tid = threadIdx.x;
    const int lane = tid & 63;
    const int w = tid >> 6;
    const int lm = lane & 15;
    const int lq = lane >> 4;      // 0..3
    const int qt = blockIdx.x, ksb = blockIdx.y, b = blockIdx.z;
    const int q0 = qt * 128;
    const int kt0 = ksb * 16, kt1 = kt0 + 16;

    __shared__ half_t Ks[64][136];   // K tile [key][d]        17,408 B
    __shared__ half_t Gts[128][72];  // G tile [d][key]        18,432 B
    __shared__ half_t Ps[128][72];   // P [q][key] wave-private 18,432 B

    half8 qh[2][4];
#pragma unroll
    for (int nb = 0; nb < 2; ++nb) {
        const half_t* tr_ = theta + ((size_t)b * N_ + q0 + w * 32 + nb * 16 + lm) * D_;
#pragma unroll
        for (int k4 = 0; k4 < 4; ++k4)
            qh[nb][k4] = *(const half8*)(tr_ + k4 * 32 + lq * 8);
    }

    float m_i[2] = {-1e30f, -1e30f};
    float l_i[2] = {0.f, 0.f};      // per-quad partial; cross-quad sum deferred
    f32x4 yacc[2][8];
#pragma unroll
    for (int mb = 0; mb < 2; ++mb)
#pragma unroll
        for (int dn = 0; dn < 8; ++dn)
#pragma unroll
            for (int r = 0; r < 4; ++r) yacc[mb][dn][r] = 0.f;

    for (int kt = kt0; kt < kt1; ++kt) {
        const int k0 = kt * 64;
        __syncthreads();
        {   // stage K [key][d] and G^T [d][key] cooperatively (coalesced)
            const int key = tid >> 2, ch = (tid & 3);
            const float4* src = (const float4*)(pphi +
                ((size_t)b * N_ + k0 + key) * D_ + ch * 32);
            float4 a0 = src[0], a1 = src[1], a2 = src[2], a3 = src[3];
            float4* dst = (float4*)&Ks[key][ch * 32];
            dst[0] = a0; dst[1] = a1; dst[2] = a2; dst[3] = a3;
            const int d = tid >> 1, kh = (tid & 1);
            const float4* gs = (const float4*)(pgT +
                ((size_t)b * D_ + d) * N_ + k0 + kh * 32);
            float4 g0 = gs[0], g1 = gs[1], g2 = gs[2], g3 = gs[3];
            float4* gd = (float4*)&Gts[d][kh * 32];
            gd[0] = g0; gd[1] = g1; gd[2] = g2; gd[3] = g3;
        }
        __syncthreads();

        // QK^T transposed: S^T[key][q]; A = K (LDS), B = Q (regs)
        f32x4 sc[4][2];
#pragma unroll
        for (int kb = 0; kb < 4; ++kb)
#pragma unroll
            for (int nb = 0; nb < 2; ++nb)
#pragma unroll
                for (int r = 0; r < 4; ++r) sc[kb][nb][r] = 0.f;
#pragma unroll
        for (int kb = 0; kb < 4; ++kb) {
#pragma unroll
            for (int k4 = 0; k4 < 4; ++k4) {
                half8 kf = *(const half8*)&Ks[kb * 16 + lm][k4 * 32 + lq * 8];
#pragma unroll
                for (int nb = 0; nb < 2; ++nb)
                    sc[kb][nb] = MFMA16x16x32(kf, qh[nb][k4], sc[kb][nb]);
            }
        }
        // mask padded key 4095 (only last tile of last split)
        if (k0 + 64 > M_) {
#pragma unroll
            for (int kb = 0; kb < 4; ++kb)
#pragma unroll
                for (int r = 0; r < 4; ++r)
                    if (k0 + kb * 16 + lq * 4 + r >= M_) {
                        sc[kb][0][r] = -1e30f; sc[kb][1][r] = -1e30f;
                    }
        }
        // online softmax (base-2); m common across quads, l per-quad partial
        float alpha[2];
#pragma unroll
        for (int nb = 0; nb < 2; ++nb) {
            float mt = -1e30f;
#pragma unroll
            for (int kb = 0; kb < 4; ++kb)
#pragma unroll
                for (int r = 0; r < 4; ++r) mt = fmaxf(mt, sc[kb][nb][r]);
            mt = fmaxf(mt, __shfl_xor(mt, 16, 64));
            mt = fmaxf(mt, __shfl_xor(mt, 32, 64));
            const float mnew = fmaxf(m_i[nb], mt);
            alpha[nb] = exp2f(m_i[nb] - mnew);
            m_i[nb] = mnew;
            float rs = 0.f;
#pragma unroll
            for (int kb = 0; kb < 4; ++kb)
#pragma unroll
                for (int r = 0; r < 4; ++r) {
                    float p = exp2f(sc[kb][nb][r] - mnew);
                    sc[kb][nb][r] = p;
                    rs += p;
                }
            l_i[nb] = l_i[nb] * alpha[nb] + rs;
            // P store: 4 consecutive keys at fixed q -> one b64 per (kb)
#pragma unroll
            for (int kb = 0; kb < 4; ++kb) {
                half4 pk;
#pragma unroll
                for (int r = 0; r < 4; ++r) pk[r] = (half_t)sc[kb][nb][r];
                *(half4*)&Ps[w * 32 + nb * 16 + lm][kb * 16 + lq * 4] = pk;
            }
        }
        // transpose alpha from (q=lm) lane layout to accumulator's (q=lq*4+r)
        float alpha_t[2][4];
#pragma unroll
        for (int mb = 0; mb < 2; ++mb)
#pragma unroll
            for (int r = 0; r < 4; ++r)
                alpha_t[mb][r] = __shfl(alpha[mb], lq * 4 + r, 16);
        // rescale accumulator
#pragma unroll
        for (int mb = 0; mb < 2; ++mb)
#pragma unroll
            for (int dn = 0; dn < 8; ++dn)
#pragma unroll
                for (int r = 0; r < 4; ++r) yacc[mb][dn][r] *= alpha_t[mb][r];
        // PV: A = P (LDS, wave-private rows), B = G^T (LDS)
        half8 pf[2][2];
#pragma unroll
        for (int mb = 0; mb < 2; ++mb)
#pragma unroll
            for (int k2 = 0; k2 < 2; ++k2)
                pf[mb][k2] = *(const half8*)&Ps[w * 32 + mb * 16 + lm][k2 * 32 + lq * 8];
#pragma unroll
        for (int dn = 0; dn < 8; ++dn) {
#pragma unroll
            for (int k2 = 0; k2 < 2; ++k2) {
                half8 gf = *(const half8*)&Gts[dn * 16 + lm][k2 * 32 + lq * 8];
                yacc[0][dn] = MFMA16x16x32(pf[0][k2], gf, yacc[0][dn]);
                yacc[1][dn] = MFMA16x16x32(pf[1][k2], gf, yacc[1][dn]);
            }
        }
    }

    // epilogue: finish l (cross-quad sum, deferred)
#pragma unroll
    for (int nb = 0; nb < 2; ++nb) {
        l_i[nb] += __shfl_xor(l_i[nb], 16, 64);
        l_i[nb] += __shfl_xor(l_i[nb], 32, 64);
    }
    half_t* yp = ypart + ((size_t)ksb * BN_ + (size_t)b * N_) * D_;
#pragma unroll
    for (int mb = 0; mb < 2; ++mb)
#pragma unroll
        for (int dn = 0; dn < 8; ++dn)
#pragma unroll
            for (int r = 0; r < 4; ++r)
                yp[(size_t)(q0 + w * 32 + mb * 16 + lq * 4 + r) * D_ + dn * 16 + lm] =
                    (half_t)yacc[mb][dn][r];
    if (lq == 0) {
#pragma unroll
        for (int nb = 0; nb < 2; ++nb) {
            const int row = q0 + w * 32 + nb * 16 + lm;
            mstat[(size_t)ksb * BN_ + (size_t)b * N_ + row] = m_i[nb];
            lstat[(size_t)ksb * BN_ + (size_t)b * N_ + row] = l_i[nb];
        }
    }
}

// ---- final (MFMA): merge 4 partials (base-2 stats), z = x + y @ Wf ----
// grid (BN_/128, 2), block 256. LDS = 38,912 B.
__global__ __launch_bounds__(256) void final_kernel(
    const half_t* __restrict__ ypart, const float* __restrict__ mstat,
    const float* __restrict__ lstat, const float* __restrict__ x,
    const half_t* __restrict__ WfT, float* __restrict__ out)
{
    const int tid = threadIdx.x;
    const int lane = tid & 63;
    const int w = tid >> 6;
    const int lm = lane & 15;
    const int lq = lane >> 4;
    const int r0 = blockIdx.x * 128;
    const int c0 = blockIdx.y * 128;

    __shared__ half_t Ys[128][72];
    __shared__ half_t Wfs[128][72];
    __shared__ float scl[KSPLIT][128];

    if (tid < 128) {
        const int row = r0 + tid;
        float mv[KSPLIT], lv[KSPLIT], wv[KSPLIT];
        float Mx = -1e30f;
#pragma unroll
        for (int s = 0; s < KSPLIT; ++s) {
            mv[s] = mstat[(size_t)s * BN_ + row];
            lv[s] = lstat[(size_t)s * BN_ + row];
            Mx = fmaxf(Mx, mv[s]);
        }
        float lsum = 0.f;
#pragma unroll
        for (int s = 0; s < KSPLIT; ++s) { wv[s] = exp2f(mv[s] - Mx); lsum += wv[s] * lv[s]; }
        const float inv = 1.f / lsum;
#pragma unroll
        for (int s = 0; s < KSPLIT; ++s) scl[s][tid] = wv[s] * inv;
    }
    __syncthreads();

    f32x4 acc[2][8];
#pragma unroll
    for (int rb = 0; rb < 2; ++rb)
#pragma unroll
        for (int nb = 0; nb < 8; ++nb)
#pragma unroll
            for (int r = 0; r < 4; ++r) acc[rb][nb][r] = 0.f;

    const int sr = tid >> 1;
    const int dd = (tid & 1) * 32;

    for (int kc = 0; kc < 2; ++kc) {
        {
            float ss[KSPLIT];
#pragma unroll
            for (int s = 0; s < KSPLIT; ++s) ss[s] = scl[s][sr];
            const size_t yb = (size_t)(r0 + sr) * D_ + kc * 64 + dd;
            half8 o[4];
#pragma unroll
            for (int q = 0; q < 4; ++q) {
                float m[8];
#pragma unroll
                for (int j = 0; j < 8; ++j) m[j] = 0.f;
#pragma unroll
                for (int s = 0; s < KSPLIT; ++s) {
                    half8 yv = *(const half8*)&ypart[(size_t)s * BN_ * D_ + yb + q * 8];
#pragma unroll
                    for (int j = 0; j < 8; ++j) m[j] += ss[s] * (float)yv[j];
                }
#pragma unroll
                for (int j = 0; j < 8; ++j) o[q][j] = (half_t)m[j];
            }
#pragma unroll
            for (int q = 0; q < 4; ++q) *(half8*)&Ys[sr][dd + q * 8] = o[q];
            const half_t* wf = WfT + (size_t)(c0 + sr) * D_ + kc * 64 + dd;
#pragma unroll
            for (int q = 0; q < 4; ++q)
                *(half8*)&Wfs[sr][dd + q * 8] = *(const half8*)&wf[q * 8];
        }
        __syncthreads();

        half8 af[2][2];
#pragma unroll
        for (int rb = 0; rb < 2; ++rb)
#pragma unroll
            for (int k2 = 0; k2 < 2; ++k2)
                af[rb][k2] = *(const half8*)&Ys[w * 32 + rb * 16 + lm][k2 * 32 + lq * 8];
#pragma unroll
        for (int nb = 0; nb < 8; ++nb) {
#pragma unroll
            for (int k2 = 0; k2 < 2; ++k2) {
                half8 bf = *(const half8*)&Wfs[nb * 16 + lm][k2 * 32 + lq * 8];
                acc[0][nb] = MFMA16x16x32(af[0][k2], bf, acc[0][nb]);
                acc[1][nb] = MFMA16x16x32(af[1][k2], bf, acc[1][nb]);
            }
        }
        __syncthreads();
    }
#pragma unroll
    for (int rb = 0; rb < 2; ++rb)
#pragma unroll
        for (int nb = 0; nb < 8; ++nb)
#pragma unroll
            for (int r = 0; r < 4; ++r) {
                const int row = r0 + w * 32 + rb * 16 + lq * 4 + r;
                const int col = c0 + nb * 16 + lm;
                out[(size_t)row * C_ + col] =
                    acc[rb][nb][r] + x[(size_t)row * C_ + col];
            }
}

extern "C" void kernel_launch(void* const* d_in, const int* in_sizes, int n_in,
                              void* d_out, int out_size, void* d_ws, size_t ws_size,
                              hipStream_t stream)
{
    const float* x  = (const float*)d_in[0];
    const float* Wt = (const float*)d_in[1];
    const float* Wp = (const float*)d_in[2];
    const float* Wg = (const float*)d_in[3];
    const float* Wf = (const float*)d_in[4];
    float* out = (float*)d_out;

    // ws (fp32 words, SEG = BN_*D_): theta f16 | pphi f16 | pgT f16 |
    // ypart f16 x4 | mstat | lstat | WT_hi | WfT  (~30 MB)
    const size_t SEG = (size_t)BN_ * D_;   // 2,097,152
    float* ws     = (float*)d_ws;
    half_t* theta = (half_t*)ws;
    half_t* pphi  = (half_t*)(ws + SEG / 2);
    half_t* pgT   = (half_t*)(ws + SEG);
    half_t* ypart = (half_t*)(ws + 3 * SEG / 2);
    float* mstat  = ws + 3 * SEG / 2 + (size_t)KSPLIT * SEG / 2;
    float* lstat  = mstat + (size_t)KSPLIT * BN_;
    half_t* WT_hi = (half_t*)(lstat + (size_t)KSPLIT * BN_);
    half_t* WfT   = WT_hi + 3 * 32768;

    prep_kernel<<<dim3(128, 4), 256, 0, stream>>>(Wt, Wp, Wg, Wf, WT_hi, WfT);
    proj_kernel<<<dim3(BN_ / 64, 3), 256, 0, stream>>>(x, WT_hi, theta, pphi, pgT);
    attn_kernel<<<dim3(N_ / 128, KSPLIT, B_), 256, 0, stream>>>(
        theta, pphi, pgT, ypart, mstat, lstat);
    final_kernel<<<dim3(BN_ / 128, 2), 256, 0, stream>>>(
        ypart, mstat, lstat, x, WfT, out);
}